// Round 11
// baseline (206.775 us; speedup 1.0000x reference)
//
#include <hip/hip_runtime.h>
#include <hip/hip_bf16.h>
#include <stdint.h>

typedef __hip_bfloat16 bf16;
typedef __attribute__((ext_vector_type(8))) short short8;
typedef __attribute__((ext_vector_type(4))) short s16x4;
typedef __attribute__((ext_vector_type(4))) float floatx4;

#define MFMA16(a, b, c) __builtin_amdgcn_mfma_f32_16x16x32_bf16(a, b, c, 0, 0, 0)
// s_waitcnt imm: vmcnt[3:0], expcnt[6:4]=7 (no wait), lgkmcnt[11:8]=15 (no wait)
#define WAIT_VM6 3958  // 6 | (7<<4) | (15<<8)
#define WAIT_VM4 3956  // 4 | (7<<4) | (15<<8)
#define WAIT_VM0 3952  // 0 | (7<<4) | (15<<8)

__device__ __forceinline__ void async_lds16(const void* g, void* l) {
  __builtin_amdgcn_global_load_lds((__attribute__((address_space(1))) const void*)g,
                                   (__attribute__((address_space(3))) void*)l, 16, 0, 0);
}

// RNE-round two non-NaN floats to bf16, packed low|high into one u32
__device__ __forceinline__ unsigned rne2(float a, float b) {
  unsigned ua = __float_as_uint(a), ub = __float_as_uint(b);
  ua = ua + 0x7FFFu + ((ua >> 16) & 1u);
  ub = ub + 0x7FFFu + ((ub >> 16) & 1u);
  return (ua >> 16) | (ub & 0xFFFF0000u);
}

// ------------- fused prep: cvt(x,K) | transpose(Wq,Wo,V) | masks -------------
__global__ __launch_bounds__(256) void prep_k(const float* __restrict__ x, bf16* __restrict__ xb,
                                              const float* __restrict__ Kf, bf16* __restrict__ Kb,
                                              const float* __restrict__ Wq, bf16* __restrict__ WqT,
                                              const float* __restrict__ Wo, bf16* __restrict__ WoT,
                                              const float* __restrict__ V, bf16* __restrict__ VTb,
                                              const int* __restrict__ kvm, const int* __restrict__ qm,
                                              float* __restrict__ kvB, float* __restrict__ qB) {
  __shared__ float tile[64][65];
  int bid = blockIdx.x, tid = threadIdx.x;
  if (bid < 8192) {  // fp32 -> bf16 elementwise, 4 elems/thread
    const float* s; bf16* d; int g = bid;
    if (g < 4096) { s = x; d = xb; } else { s = Kf; d = Kb; g -= 4096; }
    int i = (g * 256 + tid) * 4;
    float4 v = *(const float4*)(s + i);
    uint2 o = {rne2(v.x, v.y), rne2(v.z, v.w)};
    *(uint2*)(d + i) = o;
    return;
  }
  if (bid < 9744 - 16) {  // 64x64 convert+transpose tiles
    const float* s; bf16* d; int r0, c0, R, C;
    if (bid < 8704) {
      int idx = bid - 8192;
      s = (idx >> 8) ? Wo : Wq; d = (idx >> 8) ? WoT : WqT;
      int rem = idx & 255;
      r0 = (rem & 15) * 64; c0 = (rem >> 4) * 64; R = 1024; C = 1024;
    } else {
      int idx = bid - 8704;
      int m = idx >> 5;
      s = V + (size_t)m * 2048 * 64; d = VTb + (size_t)m * 2048 * 64;
      r0 = (idx & 31) * 64; c0 = 0; R = 2048; C = 64;
    }
    int tr = tid >> 2, tg = tid & 3;
#pragma unroll
    for (int k = 0; k < 4; ++k) {
      int col = tg * 16 + k * 4;
      float4 v = *(const float4*)(s + (size_t)(r0 + tr) * C + c0 + col);
      tile[tr][col] = v.x; tile[tr][col + 1] = v.y;
      tile[tr][col + 2] = v.z; tile[tr][col + 3] = v.w;
    }
    __syncthreads();
    int orow = tid >> 2, ch = tid & 3;
    bf16* drow = d + (size_t)(c0 + orow) * R + r0;
    uint4 w0, w1;
    w0.x = rne2(tile[ch * 8 + 0][orow], tile[ch * 8 + 1][orow]);
    w0.y = rne2(tile[ch * 8 + 2][orow], tile[ch * 8 + 3][orow]);
    w0.z = rne2(tile[ch * 8 + 4][orow], tile[ch * 8 + 5][orow]);
    w0.w = rne2(tile[ch * 8 + 6][orow], tile[ch * 8 + 7][orow]);
    w1.x = rne2(tile[32 + ch * 8 + 0][orow], tile[32 + ch * 8 + 1][orow]);
    w1.y = rne2(tile[32 + ch * 8 + 2][orow], tile[32 + ch * 8 + 3][orow]);
    w1.z = rne2(tile[32 + ch * 8 + 4][orow], tile[32 + ch * 8 + 5][orow]);
    w1.w = rne2(tile[32 + ch * 8 + 6][orow], tile[32 + ch * 8 + 7][orow]);
    *(uint4*)(drow + ch * 8) = w0;
    *(uint4*)(drow + 32 + ch * 8) = w1;
    return;
  }
  int i = (bid - (9744 - 16)) * 256 + tid;  // mask -> additive log2 bias
  kvB[i] = kvm[i] ? 0.0f : -3000.0f;
  qB[i]  = qm[i]  ? 0.0f : -3000.0f;
}

// ------- GEMM: C[M,N]=scale*(A @ BT^T), 128x64 tile, BK=64, LDS dbuf --------
// 16 MFMA per wave-iter (vs 8 at 64x64) to amortize the ~fixed per-iteration
// overhead (barriers, staging, addressing). dbuf + s_waitcnt vmcnt(6): wait
// covers only the PREVIOUS iter's 6 staging loads. Grid 512 -> 2 blocks/CU.
__device__ __forceinline__ void storeC(bf16* C, size_t i, float v) { C[i] = __float2bfloat16(v); }
__device__ __forceinline__ void storeC(float* C, size_t i, float v) { C[i] = v; }

template <typename OT>
__global__ __launch_bounds__(256) void gemm_bt_k(const bf16* __restrict__ A,
                                                 const bf16* __restrict__ BT,
                                                 OT* __restrict__ C,
                                                 int M, int N, int K, float scale) {
  __shared__ __align__(16) bf16 As[2][128 * 64];
  __shared__ __align__(16) bf16 Bs[2][64 * 64];
  int tid = threadIdx.x;
  int wave = tid >> 6, lane = tid & 63;
  int quad = lane >> 4, lm = lane & 15;
  int wm = wave >> 1, wn = wave & 1;   // wave tile 64x32
  int row0 = blockIdx.y * 128, col0 = blockIdx.x * 64;

  floatx4 acc[4][2];
#pragma unroll
  for (int mt = 0; mt < 4; ++mt)
#pragma unroll
    for (int nt = 0; nt < 2; ++nt) acc[mt][nt] = (floatx4){0.f, 0.f, 0.f, 0.f};

  auto stage = [&](int buf, int k0) {
#pragma unroll
    for (int ch = 0; ch < 4; ++ch) {  // A: 128x64 = 16 chunks -> 4/wave
      int e = (wave * 4 + ch) * 512 + lane * 8;
      int r = e >> 6, c16 = (e & 63) >> 3;
      int sc = (c16 ^ (r & 7)) * 8;  // XOR source swizzle for bank spread
      async_lds16(A + (size_t)(row0 + r) * K + k0 + sc, &As[buf][(wave * 4 + ch) * 512]);
    }
#pragma unroll
    for (int ch = 0; ch < 2; ++ch) {  // B: 64x64 = 8 chunks -> 2/wave
      int e = (wave * 2 + ch) * 512 + lane * 8;
      int r = e >> 6, c16 = (e & 63) >> 3;
      int sc = (c16 ^ (r & 7)) * 8;
      async_lds16(BT + (size_t)(col0 + r) * K + k0 + sc, &Bs[buf][(wave * 2 + ch) * 512]);
    }
  };

  int niter = K >> 6;  // 16
  stage(0, 0);
  for (int i = 0; i < niter; ++i) {
    __builtin_amdgcn_s_barrier();  // all waves done reading buf (i+1)&1
    if (i + 1 < niter) {
      stage((i + 1) & 1, (i + 1) << 6);
      __builtin_amdgcn_s_waitcnt(WAIT_VM6);  // prev iter's 6 loads done
    } else {
      __builtin_amdgcn_s_waitcnt(WAIT_VM0);
    }
    __builtin_amdgcn_s_barrier();  // every wave's cur staging landed
    const bf16* Ac = As[i & 1];
    const bf16* Bc = Bs[i & 1];
    int sw = lm & 7;
#pragma unroll
    for (int ks = 0; ks < 64; ks += 32) {
      short8 af[4], bfr[2];
#pragma unroll
      for (int mt = 0; mt < 4; ++mt) {
        int R = wm * 64 + mt * 16 + lm;
        af[mt] = *(const short8*)&Ac[R * 64 + ((((ks >> 3) + quad) ^ sw) * 8)];
      }
#pragma unroll
      for (int nt = 0; nt < 2; ++nt) {
        int R = wn * 32 + nt * 16 + lm;
        bfr[nt] = *(const short8*)&Bc[R * 64 + ((((ks >> 3) + quad) ^ sw) * 8)];
      }
#pragma unroll
      for (int mt = 0; mt < 4; ++mt)
#pragma unroll
        for (int nt = 0; nt < 2; ++nt)
          acc[mt][nt] = MFMA16(af[mt], bfr[nt], acc[mt][nt]);
    }
  }
#pragma unroll
  for (int mt = 0; mt < 4; ++mt)
#pragma unroll
    for (int nt = 0; nt < 2; ++nt)
#pragma unroll
      for (int j = 0; j < 4; ++j) {
        int rr = row0 + wm * 64 + mt * 16 + quad * 4 + j;
        int cc = col0 + wn * 32 + nt * 16 + lm;
        storeC(C, (size_t)rr * N + cc, acc[mt][nt][j] * scale);
      }
}

// ------- flash attention: 32 q/wave, dbuf LDS K/V, kv-split-2 ----------------
// Grid (32,16,2): x = qblk(16) | slice(2). WG = 4 waves x 32 q = 128 q;
// 1024 kv per slice = 16 iters. 32 q/wave doubles useful work per fixed
// per-iteration overhead (R8=67us at 32q beat R9/R10=73us at 16q). dbuf +
// vmcnt(4) removes the barrier drain. bf16 unnormalized partials + lpart,
// combined by combine_k. LB(256,4): R7 lesson (unified VGPR/AGPR file).
__global__ __launch_bounds__(256, 4) void attn_k(const bf16* __restrict__ Q,
                                                 const bf16* __restrict__ Km,
                                                 const bf16* __restrict__ VT,
                                                 const float* __restrict__ qB,
                                                 const float* __restrict__ kvB,
                                                 bf16* __restrict__ Opart,
                                                 float* __restrict__ lpart) {
  const float TINY = 9.313225746154785e-10f;  // 2^-30
  __shared__ __align__(16) bf16 Ks[2][64 * 64];
  __shared__ __align__(16) bf16 Vs[2][64 * 64];
  __shared__ __align__(16) float kvBs[1024];

  int tid = threadIdx.x;
  int wave = tid >> 6, lane = tid & 63;
  int quad = lane >> 4, lm = lane & 15;
  int qb = blockIdx.x & 15, slice = blockIdx.x >> 4;
  int h = blockIdx.y, b = blockIdx.z;
  int q0 = qb * 128 + wave * 32;
  int kvbeg = slice * 1024;

  const bf16* kbase = Km + (size_t)(b * 16 + h) * 2048 * 64;
  const bf16* vbase = VT + (size_t)(b * 16 + h) * 64 * 2048;
  const float* kvBb = kvB + b * 2048;

  // stage this slice's 1024 kv biases to LDS via plain loads + ds_write
  {
    float4 v0 = *(const float4*)(kvBb + kvbeg + tid * 4);
    *(float4*)&kvBs[tid * 4] = v0;
  }

  short8 aq[2][2];
  float qbias[2];
#pragma unroll
  for (int g = 0; g < 2; ++g) {
    const bf16* qp = Q + (size_t)(b * 2048 + q0 + g * 16 + lm) * 1024 + h * 64 + quad * 8;
    aq[g][0] = *(const short8*)qp;
    aq[g][1] = *(const short8*)(qp + 32);
    qbias[g] = qB[b * 2048 + q0 + g * 16 + lm];
  }

  short8 ones;
#pragma unroll
  for (int i = 0; i < 8; ++i) ones[i] = (short)0x3F80;  // bf16 1.0

  floatx4 o_acc[2][4];
  floatx4 l_acc[2];
#pragma unroll
  for (int g = 0; g < 2; ++g) {
    l_acc[g] = (floatx4){0.f, 0.f, 0.f, 0.f};
#pragma unroll
    for (int t = 0; t < 4; ++t) o_acc[g][t] = (floatx4){0.f, 0.f, 0.f, 0.f};
  }

  union S8U { short8 s8; s16x4 h[2]; unsigned u[4]; };

  auto stageKV = [&](int buf, int kv0) {
#pragma unroll
    for (int c = 0; c < 2; ++c) {  // 4 loads/wave (2 K + 2 V)
      int o = (wave * 2 + c) * 1024 + lane * 16;
      int r = o >> 7;
      int g16 = (o >> 4) & 7;
      int sc = ((g16 ^ (r & 7)) * 8);
      async_lds16(kbase + (size_t)(kv0 + r) * 64 + sc, &Ks[buf][(wave * 2 + c) * 512]);
      async_lds16(vbase + (size_t)r * 2048 + kv0 + sc, &Vs[buf][(wave * 2 + c) * 512]);
    }
  };

  auto compute = [&](int buf, int rel) {
    const bf16* Kc = Ks[buf];
    const bf16* Vc = Vs[buf];
    S8U pf[2][2];
#pragma unroll
    for (int t = 0; t < 4; ++t) {
      int R = t * 16 + lm, sw = lm & 7;
      short8 kf0 = *(const short8*)&Kc[R * 64 + ((quad ^ sw) * 8)];
      short8 kf1 = *(const short8*)&Kc[R * 64 + (((quad + 4) ^ sw) * 8)];
      floatx4 zb = *(const floatx4*)&kvBs[rel + t * 16 + quad * 4];
#pragma unroll
      for (int g = 0; g < 2; ++g) {
        floatx4 z;
#pragma unroll
        for (int j = 0; j < 4; ++j) z[j] = zb[j] + qbias[g];
        z = MFMA16(kf0, aq[g][0], z);
        z = MFMA16(kf1, aq[g][1], z);
        float p0 = __builtin_amdgcn_exp2f(z[0]) + TINY;
        float p1 = __builtin_amdgcn_exp2f(z[1]) + TINY;
        float p2 = __builtin_amdgcn_exp2f(z[2]) + TINY;
        float p3 = __builtin_amdgcn_exp2f(z[3]) + TINY;
        pf[g][t >> 1].u[(t & 1) * 2 + 0] = rne2(p0, p1);
        pf[g][t >> 1].u[(t & 1) * 2 + 1] = rne2(p2, p3);
      }
    }
#pragma unroll
    for (int t = 0; t < 4; ++t) {
      int D = t * 16 + lm, sw = lm & 7;
      int hoff = (quad & 1) * 4, qh = quad >> 1;
      S8U vf0, vf1;
      vf0.h[0] = *(const s16x4*)&Vc[D * 64 + (((0 + qh) ^ sw) * 8) + hoff];
      vf0.h[1] = *(const s16x4*)&Vc[D * 64 + (((2 + qh) ^ sw) * 8) + hoff];
      vf1.h[0] = *(const s16x4*)&Vc[D * 64 + (((4 + qh) ^ sw) * 8) + hoff];
      vf1.h[1] = *(const s16x4*)&Vc[D * 64 + (((6 + qh) ^ sw) * 8) + hoff];
#pragma unroll
      for (int g = 0; g < 2; ++g) {
        o_acc[g][t] = MFMA16(vf0.s8, pf[g][0].s8, o_acc[g][t]);
        o_acc[g][t] = MFMA16(vf1.s8, pf[g][1].s8, o_acc[g][t]);
      }
    }
#pragma unroll
    for (int g = 0; g < 2; ++g) {
      l_acc[g] = MFMA16(ones, pf[g][0].s8, l_acc[g]);
      l_acc[g] = MFMA16(ones, pf[g][1].s8, l_acc[g]);
    }
  };

  __syncthreads();  // biases visible to all waves; drains Q/bias loads
  stageKV(0, kvbeg);
  // unrolled-by-2 dbuf loop: buffer index constant at each call site
  for (int i = 0; i < 16; i += 2) {
    __builtin_amdgcn_s_barrier();
    stageKV(1, kvbeg + (i + 1) * 64);        // i+1 <= 15 always valid
    __builtin_amdgcn_s_waitcnt(WAIT_VM4);    // buf0's loads (prev) done
    __builtin_amdgcn_s_barrier();
    compute(0, i * 64);

    __builtin_amdgcn_s_barrier();
    if (i + 2 < 16) {
      stageKV(0, kvbeg + (i + 2) * 64);
      __builtin_amdgcn_s_waitcnt(WAIT_VM4);  // buf1's loads done
    } else {
      __builtin_amdgcn_s_waitcnt(WAIT_VM0);
    }
    __builtin_amdgcn_s_barrier();
    compute(1, (i + 1) * 64);
  }
  // ---- epilogue: unnormalized bf16 partials, [slice][b][q][h*64+d] ----
  bf16* Op = Opart + (size_t)slice * 4194304u;
#pragma unroll
  for (int g = 0; g < 2; ++g) {
    int q = b * 2048 + q0 + g * 16 + lm;
    bf16* orow = Op + (size_t)q * 1024 + h * 64;
#pragma unroll
    for (int t = 0; t < 4; ++t) {
      uint2 ov = {rne2(o_acc[g][t][0], o_acc[g][t][1]),
                  rne2(o_acc[g][t][2], o_acc[g][t][3])};
      *(uint2*)(orow + t * 16 + quad * 4) = ov;
    }
    if (quad == 0)
      lpart[((size_t)slice * 4096 + (size_t)q) * 16 + h] = l_acc[g][0];
  }
}

// ---------------- combine: out = bf16((O0+O1) / (l0+l1)) ----------------
__global__ void combine_k(const bf16* __restrict__ Opart, const float* __restrict__ lpart,
                          bf16* __restrict__ out) {
  int i = (blockIdx.x * 256 + threadIdx.x) * 8;  // over 2*2048*1024 elems
  int bq = i >> 10, h = (i >> 6) & 15;
  float l = lpart[bq * 16 + h] + lpart[65536 + bq * 16 + h];
  float rl = 1.0f / l;
  float acc[8];
#pragma unroll
  for (int e = 0; e < 8; ++e) acc[e] = 0.f;
#pragma unroll
  for (int s = 0; s < 2; ++s) {
    uint4 u = *(const uint4*)(Opart + s * 4194304 + i);
    acc[0] += __uint_as_float(u.x << 16); acc[1] += __uint_as_float(u.x & 0xFFFF0000u);
    acc[2] += __uint_as_float(u.y << 16); acc[3] += __uint_as_float(u.y & 0xFFFF0000u);
    acc[4] += __uint_as_float(u.z << 16); acc[5] += __uint_as_float(u.z & 0xFFFF0000u);
    acc[6] += __uint_as_float(u.w << 16); acc[7] += __uint_as_float(u.w & 0xFFFF0000u);
  }
  uint4 o = {rne2(acc[0] * rl, acc[1] * rl), rne2(acc[2] * rl, acc[3] * rl),
             rne2(acc[4] * rl, acc[5] * rl), rne2(acc[6] * rl, acc[7] * rl)};
  *(uint4*)(out + i) = o;
}

// ---------------- launch ----------------
extern "C" void kernel_launch(void* const* d_in, const int* in_sizes, int n_in,
                              void* d_out, int out_size, void* d_ws, size_t ws_size,
                              hipStream_t stream) {
  const float* x  = (const float*)d_in[0];   // [2,2048,1024] fp32
  const float* K  = (const float*)d_in[1];   // [2,16,2048,64] fp32
  const float* V  = (const float*)d_in[2];   // [2,16,2048,64] fp32
  const float* Wq = (const float*)d_in[3];   // [1024,1024] fp32
  const float* Wo = (const float*)d_in[4];   // [1024,1024] fp32
  const int* kvm  = (const int*)d_in[5];     // [2,1,1,2048] bool -> int32
  const int* qm   = (const int*)d_in[6];     // [2,1,2048,1] bool -> int32

  char* w = (char*)d_ws;
  bf16* xb    = (bf16*)(w);                        // 8 MB; reused as attnb (xb dead after gemm1)
  bf16* attnb = xb;
  bf16* Qb    = (bf16*)(w + (8u << 20));           // 8 MB (pre-scaled by log2e/sqrt(dk))
  bf16* Kb    = (bf16*)(w + (16u << 20));          // 8 MB
  bf16* VTb   = (bf16*)(w + (24u << 20));          // 8 MB [2,16,64,2048]
  bf16* WqT   = (bf16*)(w + (32u << 20));          // 2 MB
  bf16* WoT   = (bf16*)(w + (34u << 20));          // 2 MB
  float* qB   = (float*)(w + (36u << 20));         // 16 KB
  float* kvB  = (float*)(w + (36u << 20) + 16384); // 16 KB
  bf16* Opart = (bf16*)(w + (40u << 20));          // 16 MB [2][2][2048][1024] bf16
  float* lpart = (float*)(w + (72u << 20));        // 512 KB [2][4096][16] fp32

  const float SCL2 = 0.18033688011112042f;  // log2(e)/sqrt(64)

  prep_k<<<9744, 256, 0, stream>>>(x, xb, K, Kb, Wq, WqT, Wo, WoT, V, VTb, kvm, qm, kvB, qB);
  gemm_bt_k<bf16><<<dim3(16, 32), 256, 0, stream>>>(xb, WqT, Qb, 4096, 1024, 1024, SCL2);
  attn_k<<<dim3(32, 16, 2), 256, 0, stream>>>(Qb, Kb, VTb, qB, kvB, Opart, lpart);
  combine_k<<<2048, 256, 0, stream>>>(Opart, lpart, attnb);
  gemm_bt_k<float><<<dim3(16, 32), 256, 0, stream>>>(attnb, WoT, (float*)d_out, 4096, 1024, 1024, 1.0f);
}

// Round 12
// 201.097 us; speedup vs baseline: 1.0282x; 1.0282x over previous
//
#include <hip/hip_runtime.h>
#include <hip/hip_bf16.h>
#include <stdint.h>

typedef __hip_bfloat16 bf16;
typedef __attribute__((ext_vector_type(8))) short short8;
typedef __attribute__((ext_vector_type(4))) short s16x4;
typedef __attribute__((ext_vector_type(4))) float floatx4;

#define MFMA16(a, b, c) __builtin_amdgcn_mfma_f32_16x16x32_bf16(a, b, c, 0, 0, 0)
// s_waitcnt imm: vmcnt[3:0], expcnt[6:4]=7 (no wait), lgkmcnt[11:8]=15 (no wait)
#define WAIT_VM12 3964  // 12 | (7<<4) | (15<<8)
#define WAIT_VM6  3958
#define WAIT_VM4  3956
#define WAIT_VM0  3952

__device__ __forceinline__ void async_lds16(const void* g, void* l) {
  __builtin_amdgcn_global_load_lds((__attribute__((address_space(1))) const void*)g,
                                   (__attribute__((address_space(3))) void*)l, 16, 0, 0);
}

// RNE-round two non-NaN floats to bf16, packed low|high into one u32
__device__ __forceinline__ unsigned rne2(float a, float b) {
  unsigned ua = __float_as_uint(a), ub = __float_as_uint(b);
  ua = ua + 0x7FFFu + ((ua >> 16) & 1u);
  ub = ub + 0x7FFFu + ((ub >> 16) & 1u);
  return (ua >> 16) | (ub & 0xFFFF0000u);
}

// HW packed f32x2 -> bf16x2 (RNE) where available; rne2 fallback
__device__ __forceinline__ unsigned pk2(float a, float b) {
#if __has_builtin(__builtin_amdgcn_cvt_pk_bf16_f32)
  auto r = __builtin_amdgcn_cvt_pk_bf16_f32(a, b);
  return __builtin_bit_cast(unsigned, r);
#else
  return rne2(a, b);
#endif
}

// ------------- fused prep: cvt(x,K) | transpose(Wq,Wo,V) | masks -------------
__global__ __launch_bounds__(256) void prep_k(const float* __restrict__ x, bf16* __restrict__ xb,
                                              const float* __restrict__ Kf, bf16* __restrict__ Kb,
                                              const float* __restrict__ Wq, bf16* __restrict__ WqT,
                                              const float* __restrict__ Wo, bf16* __restrict__ WoT,
                                              const float* __restrict__ V, bf16* __restrict__ VTb,
                                              const int* __restrict__ kvm, const int* __restrict__ qm,
                                              float* __restrict__ kvB, float* __restrict__ qS) {
  __shared__ float tile[64][65];
  int bid = blockIdx.x, tid = threadIdx.x;
  if (bid < 8192) {  // fp32 -> bf16 elementwise, 4 elems/thread
    const float* s; bf16* d; int g = bid;
    if (g < 4096) { s = x; d = xb; } else { s = Kf; d = Kb; g -= 4096; }
    int i = (g * 256 + tid) * 4;
    float4 v = *(const float4*)(s + i);
    uint2 o = {rne2(v.x, v.y), rne2(v.z, v.w)};
    *(uint2*)(d + i) = o;
    return;
  }
  if (bid < 9744 - 16) {  // 64x64 convert+transpose tiles
    const float* s; bf16* d; int r0, c0, R, C;
    if (bid < 8704) {
      int idx = bid - 8192;
      s = (idx >> 8) ? Wo : Wq; d = (idx >> 8) ? WoT : WqT;
      int rem = idx & 255;
      r0 = (rem & 15) * 64; c0 = (rem >> 4) * 64; R = 1024; C = 1024;
    } else {
      int idx = bid - 8704;
      int m = idx >> 5;
      s = V + (size_t)m * 2048 * 64; d = VTb + (size_t)m * 2048 * 64;
      r0 = (idx & 31) * 64; c0 = 0; R = 2048; C = 64;
    }
    int tr = tid >> 2, tg = tid & 3;
#pragma unroll
    for (int k = 0; k < 4; ++k) {
      int col = tg * 16 + k * 4;
      float4 v = *(const float4*)(s + (size_t)(r0 + tr) * C + c0 + col);
      tile[tr][col] = v.x; tile[tr][col + 1] = v.y;
      tile[tr][col + 2] = v.z; tile[tr][col + 3] = v.w;
    }
    __syncthreads();
    int orow = tid >> 2, ch = tid & 3;
    bf16* drow = d + (size_t)(c0 + orow) * R + r0;
    uint4 w0, w1;
    w0.x = rne2(tile[ch * 8 + 0][orow], tile[ch * 8 + 1][orow]);
    w0.y = rne2(tile[ch * 8 + 2][orow], tile[ch * 8 + 3][orow]);
    w0.z = rne2(tile[ch * 8 + 4][orow], tile[ch * 8 + 5][orow]);
    w0.w = rne2(tile[ch * 8 + 6][orow], tile[ch * 8 + 7][orow]);
    w1.x = rne2(tile[32 + ch * 8 + 0][orow], tile[32 + ch * 8 + 1][orow]);
    w1.y = rne2(tile[32 + ch * 8 + 2][orow], tile[32 + ch * 8 + 3][orow]);
    w1.z = rne2(tile[32 + ch * 8 + 4][orow], tile[32 + ch * 8 + 5][orow]);
    w1.w = rne2(tile[32 + ch * 8 + 6][orow], tile[32 + ch * 8 + 7][orow]);
    *(uint4*)(drow + ch * 8) = w0;
    *(uint4*)(drow + 32 + ch * 8) = w1;
    return;
  }
  int i = (bid - (9744 - 16)) * 256 + tid;
  kvB[i] = kvm[i] ? 0.0f : -3000.0f;  // additive log2 bias
  qS[i]  = qm[i]  ? 1.0f : 0.0f;      // multiplicative: p = fma(exp2(z), qS, TINY)
}

// ---- GEMM: C[M,N]=scale*(A @ BT^T), 128x64 tile, BK=64, TRIPLE-buffer ------
// Prefetch distance 2 + s_waitcnt vmcnt(12): the wait covers loads issued TWO
// iterations ago (>=2 iters of compute ~1200cy > HBM ~900cy latency). R10/R11
// dbuf (distance 1, ~600cy) left every HBM-cold staging load exposed.
__device__ __forceinline__ void storeC(bf16* C, size_t i, float v) { C[i] = __float2bfloat16(v); }
__device__ __forceinline__ void storeC(float* C, size_t i, float v) { C[i] = v; }

template <typename OT>
__global__ __launch_bounds__(256) void gemm_bt_k(const bf16* __restrict__ A,
                                                 const bf16* __restrict__ BT,
                                                 OT* __restrict__ C,
                                                 int M, int N, int K, float scale) {
  __shared__ __align__(16) bf16 As[3 * 128 * 64];  // 48 KB
  __shared__ __align__(16) bf16 Bs[3 * 64 * 64];   // 24 KB
  int tid = threadIdx.x;
  int wave = tid >> 6, lane = tid & 63;
  int quad = lane >> 4, lm = lane & 15;
  int wm = wave >> 1, wn = wave & 1;   // wave tile 64x32
  int row0 = blockIdx.y * 128, col0 = blockIdx.x * 64;

  floatx4 acc[4][2];
#pragma unroll
  for (int mt = 0; mt < 4; ++mt)
#pragma unroll
    for (int nt = 0; nt < 2; ++nt) acc[mt][nt] = (floatx4){0.f, 0.f, 0.f, 0.f};

  auto stage = [&](int buf, int it) {
    int k0 = it << 6;
#pragma unroll
    for (int ch = 0; ch < 4; ++ch) {  // A: 128x64 = 16 chunks -> 4/wave
      int e = (wave * 4 + ch) * 512 + lane * 8;
      int r = e >> 6, c16 = (e & 63) >> 3;
      int sc = (c16 ^ (r & 7)) * 8;  // XOR source swizzle for bank spread
      async_lds16(A + (size_t)(row0 + r) * K + k0 + sc, &As[buf * 8192 + (wave * 4 + ch) * 512]);
    }
#pragma unroll
    for (int ch = 0; ch < 2; ++ch) {  // B: 64x64 = 8 chunks -> 2/wave
      int e = (wave * 2 + ch) * 512 + lane * 8;
      int r = e >> 6, c16 = (e & 63) >> 3;
      int sc = (c16 ^ (r & 7)) * 8;
      async_lds16(BT + (size_t)(col0 + r) * K + k0 + sc, &Bs[buf * 4096 + (wave * 2 + ch) * 512]);
    }
  };

  int niter = K >> 6;  // 16
  stage(0, 0);
  stage(1, 1);
  int put = 2, get = 0;
  for (int i = 0; i < niter; ++i) {
    __builtin_amdgcn_s_barrier();  // all waves done reading buffer `put`
    if (i + 2 < niter) {
      stage(put, i + 2);
      put = (put == 2) ? 0 : put + 1;
      __builtin_amdgcn_s_waitcnt(WAIT_VM12);  // iter i's 6 loads done (issued 2 iters ago)
    } else if (i + 1 < niter) {
      __builtin_amdgcn_s_waitcnt(WAIT_VM6);
    } else {
      __builtin_amdgcn_s_waitcnt(WAIT_VM0);
    }
    __builtin_amdgcn_s_barrier();  // every wave's iter-i staging landed
    const bf16* Ac = As + get * 8192;
    const bf16* Bc = Bs + get * 4096;
    get = (get == 2) ? 0 : get + 1;
    int sw = lm & 7;
#pragma unroll
    for (int ks = 0; ks < 64; ks += 32) {
      short8 af[4], bfr[2];
#pragma unroll
      for (int mt = 0; mt < 4; ++mt) {
        int R = wm * 64 + mt * 16 + lm;
        af[mt] = *(const short8*)&Ac[R * 64 + ((((ks >> 3) + quad) ^ sw) * 8)];
      }
#pragma unroll
      for (int nt = 0; nt < 2; ++nt) {
        int R = wn * 32 + nt * 16 + lm;
        bfr[nt] = *(const short8*)&Bc[R * 64 + ((((ks >> 3) + quad) ^ sw) * 8)];
      }
#pragma unroll
      for (int mt = 0; mt < 4; ++mt)
#pragma unroll
        for (int nt = 0; nt < 2; ++nt)
          acc[mt][nt] = MFMA16(af[mt], bfr[nt], acc[mt][nt]);
    }
  }
#pragma unroll
  for (int mt = 0; mt < 4; ++mt)
#pragma unroll
    for (int nt = 0; nt < 2; ++nt)
#pragma unroll
      for (int j = 0; j < 4; ++j) {
        int rr = row0 + wm * 64 + mt * 16 + quad * 4 + j;
        int cc = col0 + wn * 32 + nt * 16 + lm;
        storeC(C, (size_t)rr * N + cc, acc[mt][nt][j] * scale);
      }
}

// ------- flash attention: 32 q/wave, dbuf LDS K/V, kv-split-2 ----------------
// Grid (32,16,2): x = qblk(16) | slice(2). WG = 4 waves x 32 q = 128 q;
// 1024 kv per slice = 16 iters. q-mask multiplicative (exp2(-3000)=0 identity):
// p = fma(exp2(z), qS, TINY) — removes per-element qbias+TINY adds. Packing
// via v_cvt_pk_bf16_f32 where available. LB(256,4): R7 lesson (unified file).
__global__ __launch_bounds__(256, 4) void attn_k(const bf16* __restrict__ Q,
                                                 const bf16* __restrict__ Km,
                                                 const bf16* __restrict__ VT,
                                                 const float* __restrict__ qS,
                                                 const float* __restrict__ kvB,
                                                 bf16* __restrict__ Opart,
                                                 float* __restrict__ lpart) {
  const float TINY = 9.313225746154785e-10f;  // 2^-30
  __shared__ __align__(16) bf16 Ks[2 * 64 * 64];
  __shared__ __align__(16) bf16 Vs[2 * 64 * 64];
  __shared__ __align__(16) float kvBs[1024];

  int tid = threadIdx.x;
  int wave = tid >> 6, lane = tid & 63;
  int quad = lane >> 4, lm = lane & 15;
  int qb = blockIdx.x & 15, slice = blockIdx.x >> 4;
  int h = blockIdx.y, b = blockIdx.z;
  int q0 = qb * 128 + wave * 32;
  int kvbeg = slice * 1024;

  const bf16* kbase = Km + (size_t)(b * 16 + h) * 2048 * 64;
  const bf16* vbase = VT + (size_t)(b * 16 + h) * 64 * 2048;
  const float* kvBb = kvB + b * 2048;

  // stage this slice's 1024 kv biases to LDS via plain loads + ds_write
  {
    float4 v0 = *(const float4*)(kvBb + kvbeg + tid * 4);
    *(float4*)&kvBs[tid * 4] = v0;
  }

  short8 aq[2][2];
  float qscl[2];
#pragma unroll
  for (int g = 0; g < 2; ++g) {
    const bf16* qp = Q + (size_t)(b * 2048 + q0 + g * 16 + lm) * 1024 + h * 64 + quad * 8;
    aq[g][0] = *(const short8*)qp;
    aq[g][1] = *(const short8*)(qp + 32);
    qscl[g] = qS[b * 2048 + q0 + g * 16 + lm];
  }

  short8 ones;
#pragma unroll
  for (int i = 0; i < 8; ++i) ones[i] = (short)0x3F80;  // bf16 1.0

  floatx4 o_acc[2][4];
  floatx4 l_acc[2];
#pragma unroll
  for (int g = 0; g < 2; ++g) {
    l_acc[g] = (floatx4){0.f, 0.f, 0.f, 0.f};
#pragma unroll
    for (int t = 0; t < 4; ++t) o_acc[g][t] = (floatx4){0.f, 0.f, 0.f, 0.f};
  }

  union S8U { short8 s8; s16x4 h[2]; unsigned u[4]; };

  auto stageKV = [&](int buf, int kv0) {
#pragma unroll
    for (int c = 0; c < 2; ++c) {  // 4 loads/wave (2 K + 2 V)
      int o = (wave * 2 + c) * 1024 + lane * 16;
      int r = o >> 7;
      int g16 = (o >> 4) & 7;
      int sc = ((g16 ^ (r & 7)) * 8);
      async_lds16(kbase + (size_t)(kv0 + r) * 64 + sc, &Ks[buf * 4096 + (wave * 2 + c) * 512]);
      async_lds16(vbase + (size_t)r * 2048 + kv0 + sc, &Vs[buf * 4096 + (wave * 2 + c) * 512]);
    }
  };

  auto compute = [&](int buf, int rel) {
    const bf16* Kc = Ks + buf * 4096;
    const bf16* Vc = Vs + buf * 4096;
    S8U pf[2][2];
#pragma unroll
    for (int t = 0; t < 4; ++t) {
      int R = t * 16 + lm, sw = lm & 7;
      short8 kf0 = *(const short8*)&Kc[R * 64 + ((quad ^ sw) * 8)];
      short8 kf1 = *(const short8*)&Kc[R * 64 + (((quad + 4) ^ sw) * 8)];
      floatx4 zb = *(const floatx4*)&kvBs[rel + t * 16 + quad * 4];
#pragma unroll
      for (int g = 0; g < 2; ++g) {
        floatx4 z = zb;
        z = MFMA16(kf0, aq[g][0], z);
        z = MFMA16(kf1, aq[g][1], z);
        float p0 = fmaf(__builtin_amdgcn_exp2f(z[0]), qscl[g], TINY);
        float p1 = fmaf(__builtin_amdgcn_exp2f(z[1]), qscl[g], TINY);
        float p2 = fmaf(__builtin_amdgcn_exp2f(z[2]), qscl[g], TINY);
        float p3 = fmaf(__builtin_amdgcn_exp2f(z[3]), qscl[g], TINY);
        pf[g][t >> 1].u[(t & 1) * 2 + 0] = pk2(p0, p1);
        pf[g][t >> 1].u[(t & 1) * 2 + 1] = pk2(p2, p3);
      }
    }
#pragma unroll
    for (int t = 0; t < 4; ++t) {
      int D = t * 16 + lm, sw = lm & 7;
      int hoff = (quad & 1) * 4, qh = quad >> 1;
      S8U vf0, vf1;
      vf0.h[0] = *(const s16x4*)&Vc[D * 64 + (((0 + qh) ^ sw) * 8) + hoff];
      vf0.h[1] = *(const s16x4*)&Vc[D * 64 + (((2 + qh) ^ sw) * 8) + hoff];
      vf1.h[0] = *(const s16x4*)&Vc[D * 64 + (((4 + qh) ^ sw) * 8) + hoff];
      vf1.h[1] = *(const s16x4*)&Vc[D * 64 + (((6 + qh) ^ sw) * 8) + hoff];
#pragma unroll
      for (int g = 0; g < 2; ++g) {
        o_acc[g][t] = MFMA16(vf0.s8, pf[g][0].s8, o_acc[g][t]);
        o_acc[g][t] = MFMA16(vf1.s8, pf[g][1].s8, o_acc[g][t]);
      }
    }
#pragma unroll
    for (int g = 0; g < 2; ++g) {
      l_acc[g] = MFMA16(ones, pf[g][0].s8, l_acc[g]);
      l_acc[g] = MFMA16(ones, pf[g][1].s8, l_acc[g]);
    }
  };

  __syncthreads();  // biases visible to all waves; drains Q/bias loads
  stageKV(0, kvbeg);
  for (int i = 0; i < 16; i += 2) {
    __builtin_amdgcn_s_barrier();
    stageKV(1, kvbeg + (i + 1) * 64);
    __builtin_amdgcn_s_waitcnt(WAIT_VM4);    // buf0's loads (prev) done
    __builtin_amdgcn_s_barrier();
    compute(0, i * 64);

    __builtin_amdgcn_s_barrier();
    if (i + 2 < 16) {
      stageKV(0, kvbeg + (i + 2) * 64);
      __builtin_amdgcn_s_waitcnt(WAIT_VM4);  // buf1's loads done
    } else {
      __builtin_amdgcn_s_waitcnt(WAIT_VM0);
    }
    __builtin_amdgcn_s_barrier();
    compute(1, (i + 1) * 64);
  }
  // ---- epilogue: unnormalized bf16 partials, [slice][b][q][h*64+d] ----
  bf16* Op = Opart + (size_t)slice * 4194304u;
#pragma unroll
  for (int g = 0; g < 2; ++g) {
    int q = b * 2048 + q0 + g * 16 + lm;
    bf16* orow = Op + (size_t)q * 1024 + h * 64;
#pragma unroll
    for (int t = 0; t < 4; ++t) {
      uint2 ov = {pk2(o_acc[g][t][0], o_acc[g][t][1]),
                  pk2(o_acc[g][t][2], o_acc[g][t][3])};
      *(uint2*)(orow + t * 16 + quad * 4) = ov;
    }
    if (quad == 0)
      lpart[((size_t)slice * 4096 + (size_t)q) * 16 + h] = l_acc[g][0];
  }
}

// ---------------- combine: out = bf16((O0+O1) / (l0+l1)) ----------------
__global__ void combine_k(const bf16* __restrict__ Opart, const float* __restrict__ lpart,
                          bf16* __restrict__ out) {
  int i = (blockIdx.x * 256 + threadIdx.x) * 8;  // over 2*2048*1024 elems
  int bq = i >> 10, h = (i >> 6) & 15;
  float l = lpart[bq * 16 + h] + lpart[65536 + bq * 16 + h];
  float rl = 1.0f / l;
  float acc[8];
#pragma unroll
  for (int e = 0; e < 8; ++e) acc[e] = 0.f;
#pragma unroll
  for (int s = 0; s < 2; ++s) {
    uint4 u = *(const uint4*)(Opart + s * 4194304 + i);
    acc[0] += __uint_as_float(u.x << 16); acc[1] += __uint_as_float(u.x & 0xFFFF0000u);
    acc[2] += __uint_as_float(u.y << 16); acc[3] += __uint_as_float(u.y & 0xFFFF0000u);
    acc[4] += __uint_as_float(u.z << 16); acc[5] += __uint_as_float(u.z & 0xFFFF0000u);
    acc[6] += __uint_as_float(u.w << 16); acc[7] += __uint_as_float(u.w & 0xFFFF0000u);
  }
  uint4 o = {rne2(acc[0] * rl, acc[1] * rl), rne2(acc[2] * rl, acc[3] * rl),
             rne2(acc[4] * rl, acc[5] * rl), rne2(acc[6] * rl, acc[7] * rl)};
  *(uint4*)(out + i) = o;
}

// ---------------- launch ----------------
extern "C" void kernel_launch(void* const* d_in, const int* in_sizes, int n_in,
                              void* d_out, int out_size, void* d_ws, size_t ws_size,
                              hipStream_t stream) {
  const float* x  = (const float*)d_in[0];   // [2,2048,1024] fp32
  const float* K  = (const float*)d_in[1];   // [2,16,2048,64] fp32
  const float* V  = (const float*)d_in[2];   // [2,16,2048,64] fp32
  const float* Wq = (const float*)d_in[3];   // [1024,1024] fp32
  const float* Wo = (const float*)d_in[4];   // [1024,1024] fp32
  const int* kvm  = (const int*)d_in[5];     // [2,1,1,2048] bool -> int32
  const int* qm   = (const int*)d_in[6];     // [2,1,2048,1] bool -> int32

  char* w = (char*)d_ws;
  bf16* xb    = (bf16*)(w);                        // 8 MB; reused as attnb (xb dead after gemm1)
  bf16* attnb = xb;
  bf16* Qb    = (bf16*)(w + (8u << 20));           // 8 MB (pre-scaled by log2e/sqrt(dk))
  bf16* Kb    = (bf16*)(w + (16u << 20));          // 8 MB
  bf16* VTb   = (bf16*)(w + (24u << 20));          // 8 MB [2,16,64,2048]
  bf16* WqT   = (bf16*)(w + (32u << 20));          // 2 MB
  bf16* WoT   = (bf16*)(w + (34u << 20));          // 2 MB
  float* qS   = (float*)(w + (36u << 20));         // 16 KB (multiplicative q mask)
  float* kvB  = (float*)(w + (36u << 20) + 16384); // 16 KB (additive kv bias)
  bf16* Opart = (bf16*)(w + (40u << 20));          // 16 MB [2][2][2048][1024] bf16
  float* lpart = (float*)(w + (72u << 20));        // 512 KB [2][4096][16] fp32

  const float SCL2 = 0.18033688011112042f;  // log2(e)/sqrt(64)

  prep_k<<<9744, 256, 0, stream>>>(x, xb, K, Kb, Wq, WqT, Wo, WoT, V, VTb, kvm, qm, kvB, qS);
  gemm_bt_k<bf16><<<dim3(16, 32), 256, 0, stream>>>(xb, WqT, Qb, 4096, 1024, 1024, SCL2);
  attn_k<<<dim3(32, 16, 2), 256, 0, stream>>>(Qb, Kb, VTb, qS, kvB, Opart, lpart);
  combine_k<<<2048, 256, 0, stream>>>(Opart, lpart, attnb);
  gemm_bt_k<float><<<dim3(16, 32), 256, 0, stream>>>(attnb, WoT, (float*)d_out, 4096, 1024, 1024, 1.0f);
}